// Round 13
// baseline (188.282 us; speedup 1.0000x reference)
//
#include <hip/hip_runtime.h>
#include <hip/hip_bf16.h>
#include <stdint.h>

typedef __attribute__((ext_vector_type(8))) short s16x8;
typedef __attribute__((ext_vector_type(4))) float f32x4;

#define MFMA16(a, b, c) __builtin_amdgcn_mfma_f32_16x16x32_bf16((a), (b), (c), 0, 0, 0)
#define SBAR() __builtin_amdgcn_s_barrier()

__device__ __forceinline__ void gl_lds16(const void* g, void* l) {
  __builtin_amdgcn_global_load_lds(
      (__attribute__((address_space(1))) void*)(void*)g,
      (__attribute__((address_space(3))) void*)l,
      16, 0, 0);
}

__device__ __forceinline__ unsigned short f2bf(float f) {
  union { float f; uint32_t u; } c; c.f = f;
  return (unsigned short)((c.u + 0x7FFFu + ((c.u >> 16) & 1u)) >> 16);
}

// bijective XCD-aware block swizzle (m204)
__device__ __forceinline__ void xcd_swz(int GX, int GY, int& bx, int& by) {
  int nwg = GX * GY;
  int lid = by * GX + bx;
  int q = nwg >> 3, rm = nwg & 7;
  int xcd = lid & 7, off = lid >> 3;
  int nid = (xcd < rm ? xcd * (q + 1) : rm * (q + 1) + (xcd - rm) * q) + off;
  bx = nid % GX;
  by = nid / GX;
}

// ---------------- merged f32 -> bf16 convert (3 buffers, one launch) ----------------
// na4/nb4/nc4 are FLOAT4 counts.
__global__ __launch_bounds__(256) void cvt_all(
    const float* __restrict__ a, unsigned short* __restrict__ oa, int na4,
    const float* __restrict__ b, unsigned short* __restrict__ ob, int nb4,
    const float* __restrict__ c, unsigned short* __restrict__ oc, int nc4) {
  int i = blockIdx.x * 256 + threadIdx.x;
  const float* src; unsigned short* dst; int j;
  if (i < na4) { src = a; dst = oa; j = i; }
  else if (i < na4 + nb4) { src = b; dst = ob; j = i - na4; }
  else if (i < na4 + nb4 + nc4) { src = c; dst = oc; j = i - na4 - nb4; }
  else return;
  float4 v = ((const float4*)src)[j];
  ushort4 o;
  o.x = f2bf(v.x); o.y = f2bf(v.y); o.z = f2bf(v.z); o.w = f2bf(v.w);
  ((ushort4*)dst)[j] = o;
}

// ---------------- conv1d over CLS tokens (f32) ----------------
__global__ __launch_bounds__(256) void conv_cls(
    const float* __restrict__ x,
    const float* __restrict__ wq, const float* __restrict__ bq,
    const float* __restrict__ wk, const float* __restrict__ bk,
    float* __restrict__ tcq, float* __restrict__ tck) {
  __shared__ float g[768][10];  // [ci][t+1], zero-padded both ends
  const int tid = threadIdx.x;
  const int clip = blockIdx.y;
  const int chunk = blockIdx.x;  // 0..23 -> 32 co each
  for (int i = tid; i < 768 * 8; i += 256) {
    int tt = i / 768, ci = i % 768;
    g[ci][tt + 1] = x[(size_t)(clip * 8 + tt) * 151296 + ci];
  }
  for (int i = tid; i < 768; i += 256) { g[i][0] = 0.f; g[i][9] = 0.f; }
  __syncthreads();
  const int co = chunk * 32 + (tid >> 3);
  const int t = tid & 7;
  float aq = 0.f, ak = 0.f;
  const float* wqp = wq + (size_t)co * 2304;
  const float* wkp = wk + (size_t)co * 2304;
  for (int ci = 0; ci < 768; ++ci) {
    float g0 = g[ci][t], g1 = g[ci][t + 1], g2 = g[ci][t + 2];
    aq += g0 * wqp[ci * 3 + 0] + g1 * wqp[ci * 3 + 1] + g2 * wqp[ci * 3 + 2];
    ak += g0 * wkp[ci * 3 + 0] + g1 * wkp[ci * 3 + 1] + g2 * wkp[ci * 3 + 2];
  }
  int b = clip * 8 + t;
  tcq[b * 768 + co] = aq + bq[co];
  tck[b * 768 + co] = ak + bk[co];
}

// ======= fused QKV-GEMM + attention, one block per (b,h), 1024 threads =======
// Phase 1: R9 structure (verified, 104us): Xs+Ws 3-buffer gl_lds staging,
// per-wave counted vmcnt, 4Mx4N wave grid.
// Phase 2 (NEW): swapped QK^T -> mfma(K,Q): operand reads unchanged, output
// S[q=r][k=j*16+g*4+i] is lane-local in q. Scalar softmax w/ 2 shfl_xor;
// P packed to bf16-u32 pairs, 13 ds_write_b64 + 2 drains into per-wave slot
// buffer, 1 b128 read per ks regroups k for the PV A-frag.
__global__ __launch_bounds__(1024, 4) void qkv_attn(
    const unsigned short* __restrict__ X,    // x_bf 12608x768
    const unsigned short* __restrict__ Wq,   // wqkv_bf 2304x768
    const float* __restrict__ bias,          // 2304
    const float* __restrict__ tcq, const float* __restrict__ tck,  // 64x768 f32
    unsigned short* __restrict__ O) {        // ao_bf 12608x768
  union __align__(16) Smem {
    struct {  // phase-1 staging: 150 KiB
      unsigned short Xs[3][208][64];
      unsigned short Ws[3][192][64];
    } st;
    struct {  // phase-2 attention: 133 KiB
      unsigned short Qs[208][72];
      unsigned short Ks[208][72];
      unsigned short VTs[64][232];
      uint32_t Pb[13][7][16][4][2];  // per-wave P slot buffer (7 j-slots)
    } at;
  };
  __shared__ Smem U;
  __shared__ float tcb[3][64];  // fused bias (+tc)

  const int tid = threadIdx.x;
  const int w = tid >> 6, lane = tid & 63;  // w = 0..15
  int bx = blockIdx.x, by0 = 0;
  xcd_swz(gridDim.x, 1, bx, by0);  // 768 % 8 == 0: same-b heads share XCD
  const int b = bx / 12, h = bx % 12;

  if (tid < 192) {
    int sec = tid >> 6, d = tid & 63;
    float v = bias[sec * 768 + h * 64 + d];
    if (sec == 0) v += tcq[b * 768 + h * 64 + d];
    else if (sec == 1) v += tck[b * 768 + h * 64 + d];
    tcb[sec][d] = v;
  }

  const int wm = w >> 2, wn = w & 3;   // 4M x 4N wave grid for phase 1
  const int r = lane & 15, gq = lane >> 4;
  const int lrow = lane >> 3;
  const int lsw = ((lane & 7) ^ (lrow & 7)) * 8;  // inverse-swizzled 16B slot (elems)
  const int mfn = (wm == 3) ? 4 : 3;   // wm 0..2: rows wm*48..+47; wm 3: 144..207

  f32x4 acc[4][3] = {};
  const size_t xbase = (size_t)b * 197 * 768;

  // per-wave gl_lds per stage(): w<8 -> 2X+2W=4; w=8,9 -> 2X+1W=3; w>=10 -> 1X+1W=2
  auto stage = [&](int buf, int kc) {
#pragma unroll
    for (int j = 0; j < 2; ++j) {
      int c = w + j * 16;  // X chunks 0..25
      if (c < 26) {
        int row = c * 8 + lrow;
        gl_lds16(X + xbase + (size_t)row * 768 + kc * 64 + lsw,
                 (char*)&U.st.Xs[buf][0][0] + c * 1024);
      }
    }
#pragma unroll
    for (int j = 0; j < 2; ++j) {
      int c = w + j * 16;  // W chunks 0..23 (never straddle a 64-row section)
      if (c < 24) {
        int wrow = c * 8 + lrow;
        int sec = wrow >> 6;
        gl_lds16(Wq + (size_t)(sec * 768 + h * 64 + (wrow & 63)) * 768 + kc * 64 + lsw,
                 (char*)&U.st.Ws[buf][0][0] + c * 1024);
      }
    }
  };

#define WAIT_OWN()                                                 \
  do {                                                             \
    if (w < 8)       asm volatile("s_waitcnt vmcnt(4)" ::: "memory"); \
    else if (w < 10) asm volatile("s_waitcnt vmcnt(3)" ::: "memory"); \
    else             asm volatile("s_waitcnt vmcnt(2)" ::: "memory"); \
  } while (0)

  stage(0, 0);
  stage(1, 1);
  WAIT_OWN();  // tile 0 landed; tile 1 in flight
  SBAR();

  for (int kc = 0; kc < 12; ++kc) {
    const int cb = kc % 3;
    if (kc + 2 < 12) stage((kc + 2) % 3, kc + 2);  // into free buffer
    const char* xb = (const char*)&U.st.Xs[cb][0][0];
    const char* wb = (const char*)&U.st.Ws[cb][0][0];
    __builtin_amdgcn_s_setprio(1);
#pragma unroll
    for (int kk = 0; kk < 2; ++kk) {
      s16x8 bfrg[3];
#pragma unroll
      for (int nf = 0; nf < 3; ++nf) {
        int row = wn * 48 + nf * 16 + r;
        bfrg[nf] = *(const s16x8*)(wb + row * 128 + (((kk * 4 + gq) ^ (r & 7)) * 16));
      }
#pragma unroll
      for (int mf = 0; mf < 4; ++mf) {
        if (mf < mfn) {
          int row = wm * 48 + mf * 16 + r;
          s16x8 afr = *(const s16x8*)(xb + row * 128 + (((kk * 4 + gq) ^ (r & 7)) * 16));
#pragma unroll
          for (int nf = 0; nf < 3; ++nf) acc[mf][nf] = MFMA16(afr, bfrg[nf], acc[mf][nf]);
        }
      }
    }
    __builtin_amdgcn_s_setprio(0);
    if (kc < 10) {  // own just-issued loads remain; tile kc+1 guaranteed landed
      WAIT_OWN();
      SBAR();
    } else if (kc == 10) {
      asm volatile("s_waitcnt vmcnt(0)" ::: "memory");
      SBAR();
    }
  }
  __syncthreads();  // all waves done reading tile 11 before union is repurposed

  // ---- epilogue: Q/K -> LDS row-major, V -> LDS transposed; zero V^T pad cols ----
  for (int i = tid; i < 64 * 35; i += 1024) {
    int d = i / 35, c = 197 + i % 35;
    U.at.VTs[d][c] = 0;
  }
#pragma unroll
  for (int mf = 0; mf < 4; ++mf) {
    if (mf < mfn) {
#pragma unroll
      for (int nf = 0; nf < 3; ++nf) {
        int ncol = wn * 48 + nf * 16 + r;
        int sec = ncol >> 6, d = ncol & 63;
        float bb = tcb[sec][d];
#pragma unroll
        for (int rr = 0; rr < 4; ++rr) {
          int mrow = wm * 48 + mf * 16 + gq * 4 + rr;
          unsigned short bv = f2bf(acc[mf][nf][rr] + bb);
          if (sec == 0)      U.at.Qs[mrow][d] = bv;
          else if (sec == 1) U.at.Ks[mrow][d] = bv;
          else if (mrow < 197) U.at.VTs[d][mrow] = bv;  // keep garbage V out of PV MFMA
        }
      }
    }
  }
  __syncthreads();

  // ---- phase 2: swapped QK^T attention; waves 0..12 each own one 16-row q-tile ----
  const int g = gq;
  for (int qt = w; qt < 13; qt += 16) {
    const int q0 = qt * 16;
    int qrow = q0 + r; if (qrow > 196) qrow = 196;
    // B-operand = Q (free dim q = lane&15 = r): same reads as before
    s16x8 bq0 = *(const s16x8*)&U.at.Qs[qrow][g * 8];
    s16x8 bq1 = *(const s16x8*)&U.at.Qs[qrow][32 + g * 8];

    // A-operand = K (free dim k16 = lane&15 = r): same reads as before.
    // Output: lane (r,g) reg i holds S[q=q0+r][k = j*16 + g*4 + i]
    f32x4 s[13];
    __builtin_amdgcn_s_setprio(1);
#pragma unroll
    for (int j = 0; j < 13; ++j) {
      f32x4 z = {};
      z = MFMA16(*(const s16x8*)&U.at.Ks[j * 16 + r][g * 8], bq0, z);
      z = MFMA16(*(const s16x8*)&U.at.Ks[j * 16 + r][32 + g * 8], bq1, z);
      s[j] = z;
    }
    __builtin_amdgcn_s_setprio(0);
    // mask k > 196 (j=12: k = 192 + g*4 + i)
    if (g >= 2) { s[12][0] = -1e30f; s[12][1] = -1e30f; s[12][2] = -1e30f; s[12][3] = -1e30f; }
    else if (g == 1) { s[12][1] = -1e30f; s[12][2] = -1e30f; s[12][3] = -1e30f; }

    // scalar softmax over k: in-reg + 2 shfl_xor over the 4 g-groups
    float mx = s[0][0];
#pragma unroll
    for (int j = 0; j < 13; ++j)
      mx = fmaxf(mx, fmaxf(fmaxf(s[j][0], s[j][1]), fmaxf(s[j][2], s[j][3])));
    mx = fmaxf(mx, __shfl_xor(mx, 16, 64));
    mx = fmaxf(mx, __shfl_xor(mx, 32, 64));

    const float cexp = 0.125f * 1.44269504088896f;  // scale * log2(e)
    float sum = 0.f;
    uint32_t pw[13][2];
#pragma unroll
    for (int j = 0; j < 13; ++j) {
      float p0 = exp2f((s[j][0] - mx) * cexp);
      float p1 = exp2f((s[j][1] - mx) * cexp);
      float p2 = exp2f((s[j][2] - mx) * cexp);
      float p3 = exp2f((s[j][3] - mx) * cexp);
      sum += (p0 + p1) + (p2 + p3);
      pw[j][0] = ((uint32_t)f2bf(p1) << 16) | f2bf(p0);
      pw[j][1] = ((uint32_t)f2bf(p3) << 16) | f2bf(p2);
    }
    sum += __shfl_xor(sum, 16, 64);
    sum += __shfl_xor(sum, 32, 64);

    // write P tiles 0..6 into slots 0..6 (b64 each), one drain
#pragma unroll
    for (int j = 0; j < 7; ++j) {
      uint2 v; v.x = pw[j][0]; v.y = pw[j][1];
      *(uint2*)&U.at.Pb[w][j][r][g][0] = v;
    }
    asm volatile("s_waitcnt lgkmcnt(0)" ::: "memory");

    f32x4 o4[4] = {};
    s16x8 zero8 = {};
#pragma unroll
    for (int ks = 0; ks < 7; ++ks) {
      if (ks == 3) {  // refill slots 0..5 with tiles 7..12 (prior reads retired: in-order LDS)
#pragma unroll
        for (int j = 7; j < 13; ++j) {
          uint2 v; v.x = pw[j][0]; v.y = pw[j][1];
          *(uint2*)&U.at.Pb[w][j - 7][r][g][0] = v;
        }
        asm volatile("s_waitcnt lgkmcnt(0)" ::: "memory");
      }
      // A-frag: lane (r,g) needs P[q=r][k=ks*32+g*8+0..7] = tile 2ks+(g>>1), u32s at g'=2(g&1)
      const int slotA = (2 * ks) % 7, slotB = (2 * ks + 1) % 7;
      const uint32_t* pa = (g & 2) ? &U.at.Pb[w][slotB][r][2 * (g & 1)][0]
                                   : &U.at.Pb[w][slotA][r][2 * (g & 1)][0];
      s16x8 ap = *(const s16x8*)pa;
      if (ks == 6 && (g & 2)) ap = zero8;  // tile 13 doesn't exist; VT cols zeroed anyway
      __builtin_amdgcn_s_setprio(1);
#pragma unroll
      for (int n = 0; n < 4; ++n)
        o4[n] = MFMA16(ap, *(const s16x8*)&U.at.VTs[n * 16 + r][ks * 32 + g * 8], o4[n]);
      __builtin_amdgcn_s_setprio(0);
    }

    // rinv for output rows q = q0 + g*4 + rr: gather sum from lane (q', g'=0)
    float rinv[4];
#pragma unroll
    for (int rr = 0; rr < 4; ++rr) rinv[rr] = 1.0f / __shfl(sum, g * 4 + rr, 64);
#pragma unroll
    for (int n = 0; n < 4; ++n) {
#pragma unroll
      for (int rr = 0; rr < 4; ++rr) {
        int qr = q0 + g * 4 + rr;
        if (qr < 197)
          O[((size_t)(b * 197 + qr)) * 768 + h * 64 + n * 16 + r] = f2bf(o4[n][rr] * rinv[rr]);
      }
    }
  }
#undef WAIT_OWN
}

// ======= projection GEMM: BM=192 BN=128, 512 thr, 80KB LDS, grid 396 = 1 round =======
__global__ __launch_bounds__(512, 4) void proj_gemm(
    const unsigned short* __restrict__ A,   // attn out bf16 12608x768
    const unsigned short* __restrict__ Bw,  // w_proj bf16 768x768
    const float* __restrict__ bias,         // 768
    float* __restrict__ Out) {
  __shared__ __align__(16) unsigned short As[2][192][64];
  __shared__ __align__(16) unsigned short Bs[2][128][64];
  const int tid = threadIdx.x;
  const int w = tid >> 6, lane = tid & 63;
  const int wm = w >> 1, wn = w & 1;   // 4M x 2N wave grid
  const int r = lane & 15, gq = lane >> 4;
  int bx = blockIdx.x, by = blockIdx.y;
  xcd_swz(gridDim.x, gridDim.y, bx, by);
  const int m0 = by * 192, n0 = bx * 128;
  const int lrow = lane >> 3;
  const int lsw = ((lane & 7) ^ (lrow & 7)) * 8;

  f32x4 acc[3][4] = {};

  auto stage = [&](int buf, int kt) {  // 5 gl_lds per wave (3 A + 2 B)
#pragma unroll
    for (int j = 0; j < 3; ++j) {
      int c = w + j * 8;  // A chunks 0..23
      int row = c * 8 + lrow;
      gl_lds16(A + (size_t)(m0 + row) * 768 + kt * 64 + lsw, (char*)&As[buf][0][0] + c * 1024);
    }
#pragma unroll
    for (int j = 0; j < 2; ++j) {
      int c = w + j * 8;  // B chunks 0..15
      int row = c * 8 + lrow;
      gl_lds16(Bw + (size_t)(n0 + row) * 768 + kt * 64 + lsw, (char*)&Bs[buf][0][0] + c * 1024);
    }
  };

  stage(0, 0);
  stage(1, 1);
  asm volatile("s_waitcnt vmcnt(5)" ::: "memory");
  SBAR();

  for (int kt = 0; kt < 12; ++kt) {
    const int cur = kt & 1;
    s16x8 af[2][3], bfr[2][4];
#pragma unroll
    for (int kk = 0; kk < 2; ++kk) {
#pragma unroll
      for (int m = 0; m < 3; ++m) {
        int row = wm * 48 + m * 16 + r;
        af[kk][m] = *(const s16x8*)((const char*)&As[cur][0][0] + row * 128 +
                                    (((kk * 4 + gq) ^ (r & 7)) * 16));
      }
#pragma unroll
      for (int n = 0; n < 4; ++n) {
        int row = wn * 64 + n * 16 + r;
        bfr[kk][n] = *(const s16x8*)((const char*)&Bs[cur][0][0] + row * 128 +
                                     (((kk * 4 + gq) ^ (r & 7)) * 16));
      }
    }
    asm volatile("s_waitcnt lgkmcnt(0)" ::: "memory");
    __builtin_amdgcn_sched_barrier(0);
    SBAR();
    if (kt + 2 < 12) stage(cur, kt + 2);
    __builtin_amdgcn_s_setprio(1);
#pragma unroll
    for (int kk = 0; kk < 2; ++kk)
#pragma unroll
      for (int m = 0; m < 3; ++m)
#pragma unroll
        for (int n = 0; n < 4; ++n) acc[m][n] = MFMA16(af[kk][m], bfr[kk][n], acc[m][n]);
    __builtin_amdgcn_s_setprio(0);
    if (kt < 11) {
      if (kt < 10) asm volatile("s_waitcnt vmcnt(5)" ::: "memory");
      else         asm volatile("s_waitcnt vmcnt(0)" ::: "memory");
      SBAR();
    }
  }

#pragma unroll
  for (int m = 0; m < 3; ++m) {
#pragma unroll
    for (int n = 0; n < 4; ++n) {
#pragma unroll
      for (int rr = 0; rr < 4; ++rr) {
        int M = m0 + wm * 48 + m * 16 + gq * 4 + rr;
        int N = n0 + wn * 64 + n * 16 + r;
        if (M < 12608) Out[(size_t)M * 768 + N] = acc[m][n][rr] + bias[N];
      }
    }
  }
}

extern "C" void kernel_launch(void* const* d_in, const int* in_sizes, int n_in,
                              void* d_out, int out_size, void* d_ws, size_t ws_size,
                              hipStream_t stream) {
  const float* x       = (const float*)d_in[0];
  const float* w_qkv   = (const float*)d_in[1];
  const float* b_qkv   = (const float*)d_in[2];
  const float* w_proj  = (const float*)d_in[3];
  const float* b_proj  = (const float*)d_in[4];
  const float* conv_qw = (const float*)d_in[5];
  const float* conv_qb = (const float*)d_in[6];
  const float* conv_kw = (const float*)d_in[7];
  const float* conv_kb = (const float*)d_in[8];
  float* out = (float*)d_out;

  char* ws = (char*)d_ws;
  size_t off = 0;
  auto alloc = [&](size_t n) {
    char* p = ws + off;
    off = (off + n + 255) & ~(size_t)255;
    return p;
  };
  // order matters: OOB tile reads from x_bf (rows 197..207 of last b) and
  // ao_bf (proj M-tiles past 12608) must land inside the workspace
  unsigned short* x_bf    = (unsigned short*)alloc(12608ull * 768 * 2);
  unsigned short* ao_bf   = (unsigned short*)alloc(12608ull * 768 * 2);
  unsigned short* wqkv_bf = (unsigned short*)alloc(2304ull * 768 * 2);
  unsigned short* wproj_bf= (unsigned short*)alloc(768ull * 768 * 2);
  float* tcq = (float*)alloc(64 * 768 * 4);
  float* tck = (float*)alloc(64 * 768 * 4);
  if (off > ws_size) return;  // workspace too small; fail visibly

  // FLOAT4 counts
  const int na4 = 2420736, nb4 = 442368, nc4 = 147456;
  cvt_all<<<dim3((na4 + nb4 + nc4 + 255) / 256), 256, 0, stream>>>(
      x, x_bf, na4, w_qkv, wqkv_bf, nb4, w_proj, wproj_bf, nc4);
  conv_cls<<<dim3(24, 8), 256, 0, stream>>>(x, conv_qw, conv_qb, conv_kw, conv_kb, tcq, tck);
  qkv_attn<<<dim3(768), 1024, 0, stream>>>(x_bf, wqkv_bf, b_qkv, tcq, tck, ao_bf);
  proj_gemm<<<dim3(6, 66), 512, 0, stream>>>(ao_bf, wproj_bf, b_proj, out);
}

// Round 14
// 170.856 us; speedup vs baseline: 1.1020x; 1.1020x over previous
//
#include <hip/hip_runtime.h>
#include <hip/hip_bf16.h>
#include <stdint.h>

typedef __attribute__((ext_vector_type(8))) short s16x8;
typedef __attribute__((ext_vector_type(4))) float f32x4;

#define MFMA16(a, b, c) __builtin_amdgcn_mfma_f32_16x16x32_bf16((a), (b), (c), 0, 0, 0)
#define SBAR() __builtin_amdgcn_s_barrier()

__device__ __forceinline__ void gl_lds16(const void* g, void* l) {
  __builtin_amdgcn_global_load_lds(
      (__attribute__((address_space(1))) void*)(void*)g,
      (__attribute__((address_space(3))) void*)l,
      16, 0, 0);
}

__device__ __forceinline__ unsigned short f2bf(float f) {
  union { float f; uint32_t u; } c; c.f = f;
  return (unsigned short)((c.u + 0x7FFFu + ((c.u >> 16) & 1u)) >> 16);
}

__device__ __forceinline__ f32x4 max4(f32x4 a, f32x4 b) {
  f32x4 c;
  c[0] = fmaxf(a[0], b[0]); c[1] = fmaxf(a[1], b[1]);
  c[2] = fmaxf(a[2], b[2]); c[3] = fmaxf(a[3], b[3]);
  return c;
}

// bijective XCD-aware block swizzle (m204)
__device__ __forceinline__ void xcd_swz(int GX, int GY, int& bx, int& by) {
  int nwg = GX * GY;
  int lid = by * GX + bx;
  int q = nwg >> 3, rm = nwg & 7;
  int xcd = lid & 7, off = lid >> 3;
  int nid = (xcd < rm ? xcd * (q + 1) : rm * (q + 1) + (xcd - rm) * q) + off;
  bx = nid % GX;
  by = nid / GX;
}

// ======= merged conv1d (blocks 0..191) + f32->bf16 convert (rest) =======
// conv: chunk = bid % 24, clip = bid / 24. cvt: i = (bid-192)*256+tid over
// concatenated float4 ranges (na4/nb4/nc4 are FLOAT4 counts).
__global__ __launch_bounds__(256) void cvt_conv(
    const float* __restrict__ x, unsigned short* __restrict__ x_bf, int na4,
    const float* __restrict__ wqkv, unsigned short* __restrict__ wqkv_bf, int nb4,
    const float* __restrict__ wproj, unsigned short* __restrict__ wproj_bf, int nc4,
    const float* __restrict__ cqw, const float* __restrict__ cqb,
    const float* __restrict__ ckw, const float* __restrict__ ckb,
    float* __restrict__ tcq, float* __restrict__ tck) {
  const int tid = threadIdx.x;
  const int bid = blockIdx.x;
  if (bid < 192) {
    __shared__ float g[768][10];  // [ci][t+1], zero-padded both ends
    const int clip = bid / 24;
    const int chunk = bid % 24;  // 32 co each
    for (int i = tid; i < 768 * 8; i += 256) {
      int tt = i / 768, ci = i % 768;
      g[ci][tt + 1] = x[(size_t)(clip * 8 + tt) * 151296 + ci];
    }
    for (int i = tid; i < 768; i += 256) { g[i][0] = 0.f; g[i][9] = 0.f; }
    __syncthreads();
    const int co = chunk * 32 + (tid >> 3);
    const int t = tid & 7;
    float aq = 0.f, ak = 0.f;
    const float* wqp = cqw + (size_t)co * 2304;
    const float* wkp = ckw + (size_t)co * 2304;
    for (int ci = 0; ci < 768; ++ci) {
      float g0 = g[ci][t], g1 = g[ci][t + 1], g2 = g[ci][t + 2];
      aq += g0 * wqp[ci * 3 + 0] + g1 * wqp[ci * 3 + 1] + g2 * wqp[ci * 3 + 2];
      ak += g0 * wkp[ci * 3 + 0] + g1 * wkp[ci * 3 + 1] + g2 * wkp[ci * 3 + 2];
    }
    int b = clip * 8 + t;
    tcq[b * 768 + co] = aq + cqb[co];
    tck[b * 768 + co] = ak + ckb[co];
    return;
  }
  int i = (bid - 192) * 256 + tid;
  const float* src; unsigned short* dst; int j;
  if (i < na4) { src = x; dst = x_bf; j = i; }
  else if (i < na4 + nb4) { src = wqkv; dst = wqkv_bf; j = i - na4; }
  else if (i < na4 + nb4 + nc4) { src = wproj; dst = wproj_bf; j = i - na4 - nb4; }
  else return;
  float4 v = ((const float4*)src)[j];
  ushort4 o;
  o.x = f2bf(v.x); o.y = f2bf(v.y); o.z = f2bf(v.z); o.w = f2bf(v.w);
  ((ushort4*)dst)[j] = o;
}

// ======= fused QKV-GEMM + attention, one block per (b,h), 1024 threads =======
// Phase 1: R9/R12 3-buffer gl_lds staging + counted vmcnt, but the K-loop is
// FULLY UNROLLED: buffer indices, stage destinations, row offsets and tail
// branches are compile-time; swizzle offsets CSE to 2 regs. Attacks the
// VALU-address recomputation that made VALUBusy(31%) > MfmaUtil(21.5%).
// Phase 2: R12 form (16-lane-q tiles, shfl reductions, Ps transpose).
__global__ __launch_bounds__(1024, 4) void qkv_attn(
    const unsigned short* __restrict__ X,    // x_bf 12608x768
    const unsigned short* __restrict__ Wq,   // wqkv_bf 2304x768
    const float* __restrict__ bias,          // 2304
    const float* __restrict__ tcq, const float* __restrict__ tck,  // 64x768 f32
    unsigned short* __restrict__ O) {        // ao_bf 12608x768
  union __align__(16) Smem {
    struct {  // phase-1 staging: 150 KiB
      unsigned short Xs[3][208][64];
      unsigned short Ws[3][192][64];
    } st;
    struct {  // phase-2 attention: ~104 KiB
      unsigned short Qs[208][72];
      unsigned short Ks[208][72];
      unsigned short VTs[64][232];
      unsigned short Ps[13][16][40];
    } at;
  };
  __shared__ Smem U;
  __shared__ float tcb[3][64];  // fused bias (+tc)

  const int tid = threadIdx.x;
  const int w = tid >> 6, lane = tid & 63;  // w = 0..15
  int bx = blockIdx.x, by0 = 0;
  xcd_swz(gridDim.x, 1, bx, by0);  // 768 % 8 == 0: same-b heads share XCD
  const int b = bx / 12, h = bx % 12;

  if (tid < 192) {
    int sec = tid >> 6, d = tid & 63;
    float v = bias[sec * 768 + h * 64 + d];
    if (sec == 0) v += tcq[b * 768 + h * 64 + d];
    else if (sec == 1) v += tck[b * 768 + h * 64 + d];
    tcb[sec][d] = v;
  }

  const int wm = w >> 2, wn = w & 3;   // 4M x 4N wave grid for phase 1
  const int r = lane & 15, gq = lane >> 4;
  const int lrow = lane >> 3;
  const int lsw = ((lane & 7) ^ (lrow & 7)) * 8;  // inverse-swizzled 16B slot (elems)
  const int mfn = (wm == 3) ? 4 : 3;   // wm 0..2: rows wm*48..+47; wm 3: 144..207

  f32x4 acc[4][3] = {};
  const size_t xbase = (size_t)b * 197 * 768;

  // wave-invariant pieces, computed once (full unroll keeps the rest imm)
  const int swzk[2] = { ((0 + gq) ^ (r & 7)) * 16, ((4 + gq) ^ (r & 7)) * 16 };
  const int rowA = (wm * 48 + r) * 128;  // byte offset of A base row
  const int rowB = (wn * 48 + r) * 128;  // byte offset of B base row

  // per-wave gl_lds per stage(): w<8 -> 2X+2W=4; w=8,9 -> 2X+1W=3; w>=10 -> 1X+1W=2
  auto stage = [&](int buf, int kc) {
#pragma unroll
    for (int j = 0; j < 2; ++j) {
      int c = w + j * 16;  // X chunks 0..25
      if (c < 26) {
        int row = c * 8 + lrow;
        gl_lds16(X + xbase + (size_t)row * 768 + kc * 64 + lsw,
                 (char*)&U.st.Xs[buf][0][0] + c * 1024);
      }
    }
#pragma unroll
    for (int j = 0; j < 2; ++j) {
      int c = w + j * 16;  // W chunks 0..23 (never straddle a 64-row section)
      if (c < 24) {
        int wrow = c * 8 + lrow;
        int sec = wrow >> 6;
        gl_lds16(Wq + (size_t)(sec * 768 + h * 64 + (wrow & 63)) * 768 + kc * 64 + lsw,
                 (char*)&U.st.Ws[buf][0][0] + c * 1024);
      }
    }
  };

#define WAIT_OWN()                                                 \
  do {                                                             \
    if (w < 8)       asm volatile("s_waitcnt vmcnt(4)" ::: "memory"); \
    else if (w < 10) asm volatile("s_waitcnt vmcnt(3)" ::: "memory"); \
    else             asm volatile("s_waitcnt vmcnt(2)" ::: "memory"); \
  } while (0)

  stage(0, 0);
  stage(1, 1);
  WAIT_OWN();  // tile 0 landed; tile 1 in flight
  SBAR();

#pragma unroll
  for (int kc = 0; kc < 12; ++kc) {  // FULL unroll: kc, kc%3, branches all imm
    if (kc + 2 < 12) stage((kc + 2) % 3, kc + 2);  // into free buffer
    const char* xb = (const char*)&U.st.Xs[kc % 3][0][0] + rowA;
    const char* wb = (const char*)&U.st.Ws[kc % 3][0][0] + rowB;
    __builtin_amdgcn_s_setprio(1);
#pragma unroll
    for (int kk = 0; kk < 2; ++kk) {
      s16x8 bfrg[3];
#pragma unroll
      for (int nf = 0; nf < 3; ++nf)
        bfrg[nf] = *(const s16x8*)(wb + nf * 2048 + swzk[kk]);
#pragma unroll
      for (int mf = 0; mf < 4; ++mf) {
        if (mf < mfn) {
          s16x8 afr = *(const s16x8*)(xb + mf * 2048 + swzk[kk]);
#pragma unroll
          for (int nf = 0; nf < 3; ++nf) acc[mf][nf] = MFMA16(afr, bfrg[nf], acc[mf][nf]);
        }
      }
    }
    __builtin_amdgcn_s_setprio(0);
    if (kc < 10) {  // own just-issued loads remain; tile kc+1 guaranteed landed
      WAIT_OWN();
      SBAR();
    } else if (kc == 10) {
      asm volatile("s_waitcnt vmcnt(0)" ::: "memory");
      SBAR();
    }
  }
  __syncthreads();  // all waves done reading tile 11 before union is repurposed

  // ---- epilogue: Q/K -> LDS row-major, V -> LDS transposed; zero V^T pad cols ----
  for (int i = tid; i < 64 * 35; i += 1024) {
    int d = i / 35, c = 197 + i % 35;
    U.at.VTs[d][c] = 0;
  }
#pragma unroll
  for (int mf = 0; mf < 4; ++mf) {
    if (mf < mfn) {
#pragma unroll
      for (int nf = 0; nf < 3; ++nf) {
        int ncol = wn * 48 + nf * 16 + r;
        int sec = ncol >> 6, d = ncol & 63;
        float bb = tcb[sec][d];
#pragma unroll
        for (int rr = 0; rr < 4; ++rr) {
          int mrow = wm * 48 + mf * 16 + gq * 4 + rr;
          unsigned short bv = f2bf(acc[mf][nf][rr] + bb);
          if (sec == 0)      U.at.Qs[mrow][d] = bv;
          else if (sec == 1) U.at.Ks[mrow][d] = bv;
          else if (mrow < 197) U.at.VTs[d][mrow] = bv;  // keep garbage V out of PV MFMA
        }
      }
    }
  }
  __syncthreads();

  // ---- phase 2: attention; waves 0..12 each own one 16-row q-tile (R12 form) ----
  const int g = gq;
  for (int qt = w; qt < 13; qt += 16) {
    const int q0 = qt * 16;
    int qrow = q0 + r; if (qrow > 196) qrow = 196;
    s16x8 aq0 = *(const s16x8*)&U.at.Qs[qrow][g * 8];
    s16x8 aq1 = *(const s16x8*)&U.at.Qs[qrow][32 + g * 8];

    f32x4 s[13];
    __builtin_amdgcn_s_setprio(1);
#pragma unroll
    for (int j = 0; j < 13; ++j) {
      f32x4 z = {};
      z = MFMA16(aq0, *(const s16x8*)&U.at.Ks[j * 16 + r][g * 8], z);
      z = MFMA16(aq1, *(const s16x8*)&U.at.Ks[j * 16 + r][32 + g * 8], z);
      s[j] = z;
    }
    __builtin_amdgcn_s_setprio(0);
    if (r >= 5) { s[12][0] = -1e30f; s[12][1] = -1e30f; s[12][2] = -1e30f; s[12][3] = -1e30f; }

    f32x4 mx = s[0];
#pragma unroll
    for (int j = 1; j < 13; ++j) mx = max4(mx, s[j]);
#pragma unroll
    for (int off = 1; off < 16; off <<= 1) {
      f32x4 o_;
      o_[0] = __shfl_xor(mx[0], off, 64); o_[1] = __shfl_xor(mx[1], off, 64);
      o_[2] = __shfl_xor(mx[2], off, 64); o_[3] = __shfl_xor(mx[3], off, 64);
      mx = max4(mx, o_);
    }
    const float cexp = 0.125f * 1.44269504088896f;  // scale * log2(e)
    f32x4 sum = {};
#pragma unroll
    for (int j = 0; j < 13; ++j) {
      f32x4 p;
      p[0] = exp2f((s[j][0] - mx[0]) * cexp); p[1] = exp2f((s[j][1] - mx[1]) * cexp);
      p[2] = exp2f((s[j][2] - mx[2]) * cexp); p[3] = exp2f((s[j][3] - mx[3]) * cexp);
      s[j] = p;
      sum += p;
    }
#pragma unroll
    for (int off = 1; off < 16; off <<= 1) {
      sum[0] += __shfl_xor(sum[0], off, 64); sum[1] += __shfl_xor(sum[1], off, 64);
      sum[2] += __shfl_xor(sum[2], off, 64); sum[3] += __shfl_xor(sum[3], off, 64);
    }

    f32x4 o4[4] = {};
    for (int ks = 0; ks < 7; ++ks) {
      int j0 = ks * 2;
#pragma unroll
      for (int jj = 0; jj < 2; ++jj) {
        int jt = j0 + jj;
        int colb = jj * 16 + r;
        if (jt < 13) {
          f32x4 p = s[jt < 13 ? jt : 0];
          U.at.Ps[w][g * 4 + 0][colb] = f2bf(p[0]);
          U.at.Ps[w][g * 4 + 1][colb] = f2bf(p[1]);
          U.at.Ps[w][g * 4 + 2][colb] = f2bf(p[2]);
          U.at.Ps[w][g * 4 + 3][colb] = f2bf(p[3]);
        } else {
          U.at.Ps[w][g * 4 + 0][colb] = 0; U.at.Ps[w][g * 4 + 1][colb] = 0;
          U.at.Ps[w][g * 4 + 2][colb] = 0; U.at.Ps[w][g * 4 + 3][colb] = 0;
        }
      }
      asm volatile("s_waitcnt lgkmcnt(0)" ::: "memory");  // wave-local P transpose RAW
      s16x8 ap = *(const s16x8*)&U.at.Ps[w][r][g * 8];
      __builtin_amdgcn_s_setprio(1);
#pragma unroll
      for (int n = 0; n < 4; ++n)
        o4[n] = MFMA16(ap, *(const s16x8*)&U.at.VTs[n * 16 + r][ks * 32 + g * 8], o4[n]);
      __builtin_amdgcn_s_setprio(0);
    }

    f32x4 rinv;
    rinv[0] = 1.0f / sum[0]; rinv[1] = 1.0f / sum[1];
    rinv[2] = 1.0f / sum[2]; rinv[3] = 1.0f / sum[3];
#pragma unroll
    for (int n = 0; n < 4; ++n) {
#pragma unroll
      for (int rr = 0; rr < 4; ++rr) {
        int qr = q0 + g * 4 + rr;
        if (qr < 197)
          O[((size_t)(b * 197 + qr)) * 768 + h * 64 + n * 16 + r] = f2bf(o4[n][rr] * rinv[rr]);
      }
    }
  }
#undef WAIT_OWN
}

// ======= projection GEMM: BM=192 BN=128, 512 thr, 80KB LDS, grid 396 = 1 round =======
__global__ __launch_bounds__(512, 4) void proj_gemm(
    const unsigned short* __restrict__ A,   // attn out bf16 12608x768
    const unsigned short* __restrict__ Bw,  // w_proj bf16 768x768
    const float* __restrict__ bias,         // 768
    float* __restrict__ Out) {
  __shared__ __align__(16) unsigned short As[2][192][64];
  __shared__ __align__(16) unsigned short Bs[2][128][64];
  const int tid = threadIdx.x;
  const int w = tid >> 6, lane = tid & 63;
  const int wm = w >> 1, wn = w & 1;   // 4M x 2N wave grid
  const int r = lane & 15, gq = lane >> 4;
  int bx = blockIdx.x, by = blockIdx.y;
  xcd_swz(gridDim.x, gridDim.y, bx, by);
  const int m0 = by * 192, n0 = bx * 128;
  const int lrow = lane >> 3;
  const int lsw = ((lane & 7) ^ (lrow & 7)) * 8;

  f32x4 acc[3][4] = {};

  auto stage = [&](int buf, int kt) {  // 5 gl_lds per wave (3 A + 2 B)
#pragma unroll
    for (int j = 0; j < 3; ++j) {
      int c = w + j * 8;  // A chunks 0..23
      int row = c * 8 + lrow;
      gl_lds16(A + (size_t)(m0 + row) * 768 + kt * 64 + lsw, (char*)&As[buf][0][0] + c * 1024);
    }
#pragma unroll
    for (int j = 0; j < 2; ++j) {
      int c = w + j * 8;  // B chunks 0..15
      int row = c * 8 + lrow;
      gl_lds16(Bw + (size_t)(n0 + row) * 768 + kt * 64 + lsw, (char*)&Bs[buf][0][0] + c * 1024);
    }
  };

  stage(0, 0);
  stage(1, 1);
  asm volatile("s_waitcnt vmcnt(5)" ::: "memory");
  SBAR();

#pragma unroll
  for (int kt = 0; kt < 12; ++kt) {
    const int cur = kt & 1;
    s16x8 af[2][3], bfr[2][4];
#pragma unroll
    for (int kk = 0; kk < 2; ++kk) {
#pragma unroll
      for (int m = 0; m < 3; ++m) {
        int row = wm * 48 + m * 16 + r;
        af[kk][m] = *(const s16x8*)((const char*)&As[cur][0][0] + row * 128 +
                                    (((kk * 4 + gq) ^ (r & 7)) * 16));
      }
#pragma unroll
      for (int n = 0; n < 4; ++n) {
        int row = wn * 64 + n * 16 + r;
        bfr[kk][n] = *(const s16x8*)((const char*)&Bs[cur][0][0] + row * 128 +
                                     (((kk * 4 + gq) ^ (r & 7)) * 16));
      }
    }
    asm volatile("s_waitcnt lgkmcnt(0)" ::: "memory");
    __builtin_amdgcn_sched_barrier(0);
    SBAR();
    if (kt + 2 < 12) stage(cur, kt + 2);
    __builtin_amdgcn_s_setprio(1);
#pragma unroll
    for (int kk = 0; kk < 2; ++kk)
#pragma unroll
      for (int m = 0; m < 3; ++m)
#pragma unroll
        for (int n = 0; n < 4; ++n) acc[m][n] = MFMA16(af[kk][m], bfr[kk][n], acc[m][n]);
    __builtin_amdgcn_s_setprio(0);
    if (kt < 11) {
      if (kt < 10) asm volatile("s_waitcnt vmcnt(5)" ::: "memory");
      else         asm volatile("s_waitcnt vmcnt(0)" ::: "memory");
      SBAR();
    }
  }

#pragma unroll
  for (int m = 0; m < 3; ++m) {
#pragma unroll
    for (int n = 0; n < 4; ++n) {
#pragma unroll
      for (int rr = 0; rr < 4; ++rr) {
        int M = m0 + wm * 48 + m * 16 + gq * 4 + rr;
        int N = n0 + wn * 64 + n * 16 + r;
        if (M < 12608) Out[(size_t)M * 768 + N] = acc[m][n][rr] + bias[N];
      }
    }
  }
}

extern "C" void kernel_launch(void* const* d_in, const int* in_sizes, int n_in,
                              void* d_out, int out_size, void* d_ws, size_t ws_size,
                              hipStream_t stream) {
  const float* x       = (const float*)d_in[0];
  const float* w_qkv   = (const float*)d_in[1];
  const float* b_qkv   = (const float*)d_in[2];
  const float* w_proj  = (const float*)d_in[3];
  const float* b_proj  = (const float*)d_in[4];
  const float* conv_qw = (const float*)d_in[5];
  const float* conv_qb = (const float*)d_in[6];
  const float* conv_kw = (const float*)d_in[7];
  const float* conv_kb = (const float*)d_in[8];
  float* out = (float*)d_out;

  char* ws = (char*)d_ws;
  size_t off = 0;
  auto alloc = [&](size_t n) {
    char* p = ws + off;
    off = (off + n + 255) & ~(size_t)255;
    return p;
  };
  // order matters: OOB tile reads from x_bf (rows 197..207 of last b) and
  // ao_bf (proj M-tiles past 12608) must land inside the workspace
  unsigned short* x_bf    = (unsigned short*)alloc(12608ull * 768 * 2);
  unsigned short* ao_bf   = (unsigned short*)alloc(12608ull * 768 * 2);
  unsigned short* wqkv_bf = (unsigned short*)alloc(2304ull * 768 * 2);
  unsigned short* wproj_bf= (unsigned short*)alloc(768ull * 768 * 2);
  float* tcq = (float*)alloc(64 * 768 * 4);
  float* tck = (float*)alloc(64 * 768 * 4);
  if (off > ws_size) return;  // workspace too small; fail visibly

  // FLOAT4 counts
  const int na4 = 2420736, nb4 = 442368, nc4 = 147456;
  const int cvt_blocks = (na4 + nb4 + nc4 + 255) / 256;
  cvt_conv<<<dim3(192 + cvt_blocks), 256, 0, stream>>>(
      x, x_bf, na4, w_qkv, wqkv_bf, nb4, w_proj, wproj_bf, nc4,
      conv_qw, conv_qb, conv_kw, conv_kb, tcq, tck);
  qkv_attn<<<dim3(768), 1024, 0, stream>>>(x_bf, wqkv_bf, b_qkv, tcq, tck, ao_bf);
  proj_gemm<<<dim3(6, 66), 512, 0, stream>>>(ao_bf, wproj_bf, b_proj, out);
}

// Round 15
// 152.681 us; speedup vs baseline: 1.2332x; 1.1190x over previous
//
#include <hip/hip_runtime.h>
#include <hip/hip_bf16.h>
#include <stdint.h>

typedef __attribute__((ext_vector_type(8))) short s16x8;
typedef __attribute__((ext_vector_type(4))) float f32x4;

#define MFMA16(a, b, c) __builtin_amdgcn_mfma_f32_16x16x32_bf16((a), (b), (c), 0, 0, 0)
#define SBAR() __builtin_amdgcn_s_barrier()

__device__ __forceinline__ void gl_lds16(const void* g, void* l) {
  __builtin_amdgcn_global_load_lds(
      (__attribute__((address_space(1))) void*)(void*)g,
      (__attribute__((address_space(3))) void*)l,
      16, 0, 0);
}

__device__ __forceinline__ unsigned short f2bf(float f) {
  union { float f; uint32_t u; } c; c.f = f;
  return (unsigned short)((c.u + 0x7FFFu + ((c.u >> 16) & 1u)) >> 16);
}

__device__ __forceinline__ f32x4 max4(f32x4 a, f32x4 b) {
  f32x4 c;
  c[0] = fmaxf(a[0], b[0]); c[1] = fmaxf(a[1], b[1]);
  c[2] = fmaxf(a[2], b[2]); c[3] = fmaxf(a[3], b[3]);
  return c;
}

// bijective XCD-aware block swizzle (m204)
__device__ __forceinline__ void xcd_swz(int GX, int GY, int& bx, int& by) {
  int nwg = GX * GY;
  int lid = by * GX + bx;
  int q = nwg >> 3, rm = nwg & 7;
  int xcd = lid & 7, off = lid >> 3;
  int nid = (xcd < rm ? xcd * (q + 1) : rm * (q + 1) + (xcd - rm) * q) + off;
  bx = nid % GX;
  by = nid / GX;
}

// ======= merged conv1d (blocks 0..767, ci split 4 ways) + f32->bf16 cvt (rest) =======
// conv: bid -> (clip = bid/96, chunk = (bid%96)>>2 -> 32 co, part = bid&3 -> 192 ci).
// Writes PARTIAL sums (no bias) to tcpq/tcpk[part]; qkv_attn sums them + bias.
// cvt: i = (bid-768)*256+tid over concatenated float4 ranges (na4/nb4/nc4 = FLOAT4 counts).
__global__ __launch_bounds__(256) void cvt_conv(
    const float* __restrict__ x, unsigned short* __restrict__ x_bf, int na4,
    const float* __restrict__ wqkv, unsigned short* __restrict__ wqkv_bf, int nb4,
    const float* __restrict__ wproj, unsigned short* __restrict__ wproj_bf, int nc4,
    const float* __restrict__ cqw, const float* __restrict__ ckw,
    float* __restrict__ tcpq, float* __restrict__ tcpk) {
  const int tid = threadIdx.x;
  const int bid = blockIdx.x;
  if (bid < 768) {
    __shared__ float g[192][10];  // [ci_local][t+1], zero-padded both t-ends
    const int clip = bid / 96;
    const int rem = bid % 96;
    const int chunk = rem >> 2;  // 0..23 -> 32 co
    const int part = rem & 3;    // ci0 = part*192
    const int ci0 = part * 192;
    for (int i = tid; i < 192 * 8; i += 256) {
      int tt = i / 192, ci = i % 192;
      g[ci][tt + 1] = x[(size_t)(clip * 8 + tt) * 151296 + ci0 + ci];
    }
    for (int i = tid; i < 192; i += 256) { g[i][0] = 0.f; g[i][9] = 0.f; }
    __syncthreads();
    const int co = chunk * 32 + (tid >> 3);
    const int t = tid & 7;
    float aq = 0.f, ak = 0.f;
    const float* wqp = cqw + (size_t)co * 2304 + ci0 * 3;
    const float* wkp = ckw + (size_t)co * 2304 + ci0 * 3;
    for (int ci = 0; ci < 192; ++ci) {
      float g0 = g[ci][t], g1 = g[ci][t + 1], g2 = g[ci][t + 2];
      aq += g0 * wqp[ci * 3 + 0] + g1 * wqp[ci * 3 + 1] + g2 * wqp[ci * 3 + 2];
      ak += g0 * wkp[ci * 3 + 0] + g1 * wkp[ci * 3 + 1] + g2 * wkp[ci * 3 + 2];
    }
    int b = clip * 8 + t;
    tcpq[part * 49152 + b * 768 + co] = aq;
    tcpk[part * 49152 + b * 768 + co] = ak;
    return;
  }
  int i = (bid - 768) * 256 + tid;
  const float* src; unsigned short* dst; int j;
  if (i < na4) { src = x; dst = x_bf; j = i; }
  else if (i < na4 + nb4) { src = wqkv; dst = wqkv_bf; j = i - na4; }
  else if (i < na4 + nb4 + nc4) { src = wproj; dst = wproj_bf; j = i - na4 - nb4; }
  else return;
  float4 v = ((const float4*)src)[j];
  ushort4 o;
  o.x = f2bf(v.x); o.y = f2bf(v.y); o.z = f2bf(v.z); o.w = f2bf(v.w);
  ((ushort4*)dst)[j] = o;
}

// ======= fused QKV-GEMM + attention, one block per (b,h), 1024 threads =======
// R14 structure (benched 94.2us): fully-unrolled 3-buffer gl_lds pipeline +
// counted per-wave vmcnt; phase 2 = 16-lane-q tiles + shfl reductions.
// Only change vs R14: tcb loader sums the 4 conv partials + bias.
__global__ __launch_bounds__(1024, 4) void qkv_attn(
    const unsigned short* __restrict__ X,    // x_bf 12608x768
    const unsigned short* __restrict__ Wq,   // wqkv_bf 2304x768
    const float* __restrict__ bias,          // 2304
    const float* __restrict__ tcpq, const float* __restrict__ tcpk,  // 4x64x768 partials
    unsigned short* __restrict__ O) {        // ao_bf 12608x768
  union __align__(16) Smem {
    struct {  // phase-1 staging: 150 KiB
      unsigned short Xs[3][208][64];
      unsigned short Ws[3][192][64];
    } st;
    struct {  // phase-2 attention: ~104 KiB
      unsigned short Qs[208][72];
      unsigned short Ks[208][72];
      unsigned short VTs[64][232];
      unsigned short Ps[13][16][40];
    } at;
  };
  __shared__ Smem U;
  __shared__ float tcb[3][64];  // fused bias (+tc)

  const int tid = threadIdx.x;
  const int w = tid >> 6, lane = tid & 63;  // w = 0..15
  int bx = blockIdx.x, by0 = 0;
  xcd_swz(gridDim.x, 1, bx, by0);  // 768 % 8 == 0: same-b heads share XCD
  const int b = bx / 12, h = bx % 12;

  if (tid < 192) {
    int sec = tid >> 6, d = tid & 63;
    float v = bias[sec * 768 + h * 64 + d];
    if (sec < 2) {
      const float* tp = (sec == 0) ? tcpq : tcpk;
      int idx = b * 768 + h * 64 + d;
#pragma unroll
      for (int p = 0; p < 4; ++p) v += tp[p * 49152 + idx];
    }
    tcb[sec][d] = v;
  }

  const int wm = w >> 2, wn = w & 3;   // 4M x 4N wave grid for phase 1
  const int r = lane & 15, gq = lane >> 4;
  const int lrow = lane >> 3;
  const int lsw = ((lane & 7) ^ (lrow & 7)) * 8;  // inverse-swizzled 16B slot (elems)
  const int mfn = (wm == 3) ? 4 : 3;   // wm 0..2: rows wm*48..+47; wm 3: 144..207

  f32x4 acc[4][3] = {};
  const size_t xbase = (size_t)b * 197 * 768;

  // wave-invariant pieces, computed once (full unroll keeps the rest imm)
  const int swzk[2] = { ((0 + gq) ^ (r & 7)) * 16, ((4 + gq) ^ (r & 7)) * 16 };
  const int rowA = (wm * 48 + r) * 128;  // byte offset of A base row
  const int rowB = (wn * 48 + r) * 128;  // byte offset of B base row

  auto stage = [&](int buf, int kc) {
#pragma unroll
    for (int j = 0; j < 2; ++j) {
      int c = w + j * 16;  // X chunks 0..25
      if (c < 26) {
        int row = c * 8 + lrow;
        gl_lds16(X + xbase + (size_t)row * 768 + kc * 64 + lsw,
                 (char*)&U.st.Xs[buf][0][0] + c * 1024);
      }
    }
#pragma unroll
    for (int j = 0; j < 2; ++j) {
      int c = w + j * 16;  // W chunks 0..23 (never straddle a 64-row section)
      if (c < 24) {
        int wrow = c * 8 + lrow;
        int sec = wrow >> 6;
        gl_lds16(Wq + (size_t)(sec * 768 + h * 64 + (wrow & 63)) * 768 + kc * 64 + lsw,
                 (char*)&U.st.Ws[buf][0][0] + c * 1024);
      }
    }
  };

#define WAIT_OWN()                                                 \
  do {                                                             \
    if (w < 8)       asm volatile("s_waitcnt vmcnt(4)" ::: "memory"); \
    else if (w < 10) asm volatile("s_waitcnt vmcnt(3)" ::: "memory"); \
    else             asm volatile("s_waitcnt vmcnt(2)" ::: "memory"); \
  } while (0)

  stage(0, 0);
  stage(1, 1);
  WAIT_OWN();  // tile 0 landed; tile 1 in flight
  SBAR();

#pragma unroll
  for (int kc = 0; kc < 12; ++kc) {  // FULL unroll: kc, kc%3, branches all imm
    if (kc + 2 < 12) stage((kc + 2) % 3, kc + 2);  // into free buffer
    const char* xb = (const char*)&U.st.Xs[kc % 3][0][0] + rowA;
    const char* wb = (const char*)&U.st.Ws[kc % 3][0][0] + rowB;
    __builtin_amdgcn_s_setprio(1);
#pragma unroll
    for (int kk = 0; kk < 2; ++kk) {
      s16x8 bfrg[3];
#pragma unroll
      for (int nf = 0; nf < 3; ++nf)
        bfrg[nf] = *(const s16x8*)(wb + nf * 2048 + swzk[kk]);
#pragma unroll
      for (int mf = 0; mf < 4; ++mf) {
        if (mf < mfn) {
          s16x8 afr = *(const s16x8*)(xb + mf * 2048 + swzk[kk]);
#pragma unroll
          for (int nf = 0; nf < 3; ++nf) acc[mf][nf] = MFMA16(afr, bfrg[nf], acc[mf][nf]);
        }
      }
    }
    __builtin_amdgcn_s_setprio(0);
    if (kc < 10) {  // own just-issued loads remain; tile kc+1 guaranteed landed
      WAIT_OWN();
      SBAR();
    } else if (kc == 10) {
      asm volatile("s_waitcnt vmcnt(0)" ::: "memory");
      SBAR();
    }
  }
  __syncthreads();  // all waves done reading tile 11 before union is repurposed

  // ---- epilogue: Q/K -> LDS row-major, V -> LDS transposed; zero V^T pad cols ----
  for (int i = tid; i < 64 * 35; i += 1024) {
    int d = i / 35, c = 197 + i % 35;
    U.at.VTs[d][c] = 0;
  }
#pragma unroll
  for (int mf = 0; mf < 4; ++mf) {
    if (mf < mfn) {
#pragma unroll
      for (int nf = 0; nf < 3; ++nf) {
        int ncol = wn * 48 + nf * 16 + r;
        int sec = ncol >> 6, d = ncol & 63;
        float bb = tcb[sec][d];
#pragma unroll
        for (int rr = 0; rr < 4; ++rr) {
          int mrow = wm * 48 + mf * 16 + gq * 4 + rr;
          unsigned short bv = f2bf(acc[mf][nf][rr] + bb);
          if (sec == 0)      U.at.Qs[mrow][d] = bv;
          else if (sec == 1) U.at.Ks[mrow][d] = bv;
          else if (mrow < 197) U.at.VTs[d][mrow] = bv;  // keep garbage V out of PV MFMA
        }
      }
    }
  }
  __syncthreads();

  // ---- phase 2: attention; waves 0..12 each own one 16-row q-tile ----
  const int g = gq;
  for (int qt = w; qt < 13; qt += 16) {
    const int q0 = qt * 16;
    int qrow = q0 + r; if (qrow > 196) qrow = 196;
    s16x8 aq0 = *(const s16x8*)&U.at.Qs[qrow][g * 8];
    s16x8 aq1 = *(const s16x8*)&U.at.Qs[qrow][32 + g * 8];

    f32x4 s[13];
    __builtin_amdgcn_s_setprio(1);
#pragma unroll
    for (int j = 0; j < 13; ++j) {
      f32x4 z = {};
      z = MFMA16(aq0, *(const s16x8*)&U.at.Ks[j * 16 + r][g * 8], z);
      z = MFMA16(aq1, *(const s16x8*)&U.at.Ks[j * 16 + r][32 + g * 8], z);
      s[j] = z;
    }
    __builtin_amdgcn_s_setprio(0);
    if (r >= 5) { s[12][0] = -1e30f; s[12][1] = -1e30f; s[12][2] = -1e30f; s[12][3] = -1e30f; }

    f32x4 mx = s[0];
#pragma unroll
    for (int j = 1; j < 13; ++j) mx = max4(mx, s[j]);
#pragma unroll
    for (int off = 1; off < 16; off <<= 1) {
      f32x4 o_;
      o_[0] = __shfl_xor(mx[0], off, 64); o_[1] = __shfl_xor(mx[1], off, 64);
      o_[2] = __shfl_xor(mx[2], off, 64); o_[3] = __shfl_xor(mx[3], off, 64);
      mx = max4(mx, o_);
    }
    const float cexp = 0.125f * 1.44269504088896f;  // scale * log2(e)
    f32x4 sum = {};
#pragma unroll
    for (int j = 0; j < 13; ++j) {
      f32x4 p;
      p[0] = exp2f((s[j][0] - mx[0]) * cexp); p[1] = exp2f((s[j][1] - mx[1]) * cexp);
      p[2] = exp2f((s[j][2] - mx[2]) * cexp); p[3] = exp2f((s[j][3] - mx[3]) * cexp);
      s[j] = p;
      sum += p;
    }
#pragma unroll
    for (int off = 1; off < 16; off <<= 1) {
      sum[0] += __shfl_xor(sum[0], off, 64); sum[1] += __shfl_xor(sum[1], off, 64);
      sum[2] += __shfl_xor(sum[2], off, 64); sum[3] += __shfl_xor(sum[3], off, 64);
    }

    f32x4 o4[4] = {};
    for (int ks = 0; ks < 7; ++ks) {
      int j0 = ks * 2;
#pragma unroll
      for (int jj = 0; jj < 2; ++jj) {
        int jt = j0 + jj;
        int colb = jj * 16 + r;
        if (jt < 13) {
          f32x4 p = s[jt < 13 ? jt : 0];
          U.at.Ps[w][g * 4 + 0][colb] = f2bf(p[0]);
          U.at.Ps[w][g * 4 + 1][colb] = f2bf(p[1]);
          U.at.Ps[w][g * 4 + 2][colb] = f2bf(p[2]);
          U.at.Ps[w][g * 4 + 3][colb] = f2bf(p[3]);
        } else {
          U.at.Ps[w][g * 4 + 0][colb] = 0; U.at.Ps[w][g * 4 + 1][colb] = 0;
          U.at.Ps[w][g * 4 + 2][colb] = 0; U.at.Ps[w][g * 4 + 3][colb] = 0;
        }
      }
      asm volatile("s_waitcnt lgkmcnt(0)" ::: "memory");  // wave-local P transpose RAW
      s16x8 ap = *(const s16x8*)&U.at.Ps[w][r][g * 8];
      __builtin_amdgcn_s_setprio(1);
#pragma unroll
      for (int n = 0; n < 4; ++n)
        o4[n] = MFMA16(ap, *(const s16x8*)&U.at.VTs[n * 16 + r][ks * 32 + g * 8], o4[n]);
      __builtin_amdgcn_s_setprio(0);
    }

    f32x4 rinv;
    rinv[0] = 1.0f / sum[0]; rinv[1] = 1.0f / sum[1];
    rinv[2] = 1.0f / sum[2]; rinv[3] = 1.0f / sum[3];
#pragma unroll
    for (int n = 0; n < 4; ++n) {
#pragma unroll
      for (int rr = 0; rr < 4; ++rr) {
        int qr = q0 + g * 4 + rr;
        if (qr < 197)
          O[((size_t)(b * 197 + qr)) * 768 + h * 64 + n * 16 + r] = f2bf(o4[n][rr] * rinv[rr]);
      }
    }
  }
#undef WAIT_OWN
}

// ======= projection GEMM: phase-1 clone, 208x192 per block, grid 256 = 1 round =======
// block (b = bx>>2, nt = bx&3): Out[b*197 + 0..196][nt*192 .. +191].
// Rows 197..207 computed on garbage and masked at the write (avoids b-collision).
__global__ __launch_bounds__(1024, 4) void proj_gemm(
    const unsigned short* __restrict__ A,   // ao_bf 12608x768
    const unsigned short* __restrict__ Bw,  // wproj_bf 768x768
    const float* __restrict__ bias,         // 768
    float* __restrict__ Out) {
  __shared__ __align__(16) unsigned short Xs[3][208][64];
  __shared__ __align__(16) unsigned short Ws[3][192][64];
  const int tid = threadIdx.x;
  const int w = tid >> 6, lane = tid & 63;
  int bx = blockIdx.x, by0 = 0;
  xcd_swz(gridDim.x, 1, bx, by0);  // 256 % 8 == 0: bijective
  const int b = bx >> 2, nt = bx & 3;
  const int wm = w >> 2, wn = w & 3;
  const int r = lane & 15, gq = lane >> 4;
  const int lrow = lane >> 3;
  const int lsw = ((lane & 7) ^ (lrow & 7)) * 8;
  const int mfn = (wm == 3) ? 4 : 3;

  f32x4 acc[4][3] = {};
  const size_t abase = (size_t)b * 197 * 768;
  const int swzk[2] = { ((0 + gq) ^ (r & 7)) * 16, ((4 + gq) ^ (r & 7)) * 16 };
  const int rowA = (wm * 48 + r) * 128;
  const int rowB = (wn * 48 + r) * 128;

  auto stage = [&](int buf, int kc) {
#pragma unroll
    for (int j = 0; j < 2; ++j) {
      int c = w + j * 16;  // A chunks 0..25 (rows b*197 .. +207; tail reads past ao into ws: safe)
      if (c < 26) {
        int row = c * 8 + lrow;
        gl_lds16(A + abase + (size_t)row * 768 + kc * 64 + lsw,
                 (char*)&Xs[buf][0][0] + c * 1024);
      }
    }
#pragma unroll
    for (int j = 0; j < 2; ++j) {
      int c = w + j * 16;  // W chunks 0..23 (rows nt*192 .. +191)
      if (c < 24) {
        int wrow = c * 8 + lrow;
        gl_lds16(Bw + (size_t)(nt * 192 + wrow) * 768 + kc * 64 + lsw,
                 (char*)&Ws[buf][0][0] + c * 1024);
      }
    }
  };

#define WAIT_OWN()                                                 \
  do {                                                             \
    if (w < 8)       asm volatile("s_waitcnt vmcnt(4)" ::: "memory"); \
    else if (w < 10) asm volatile("s_waitcnt vmcnt(3)" ::: "memory"); \
    else             asm volatile("s_waitcnt vmcnt(2)" ::: "memory"); \
  } while (0)

  stage(0, 0);
  stage(1, 1);
  WAIT_OWN();
  SBAR();

#pragma unroll
  for (int kc = 0; kc < 12; ++kc) {
    if (kc + 2 < 12) stage((kc + 2) % 3, kc + 2);
    const char* xb = (const char*)&Xs[kc % 3][0][0] + rowA;
    const char* wb = (const char*)&Ws[kc % 3][0][0] + rowB;
    __builtin_amdgcn_s_setprio(1);
#pragma unroll
    for (int kk = 0; kk < 2; ++kk) {
      s16x8 bfrg[3];
#pragma unroll
      for (int nf = 0; nf < 3; ++nf)
        bfrg[nf] = *(const s16x8*)(wb + nf * 2048 + swzk[kk]);
#pragma unroll
      for (int mf = 0; mf < 4; ++mf) {
        if (mf < mfn) {
          s16x8 afr = *(const s16x8*)(xb + mf * 2048 + swzk[kk]);
#pragma unroll
          for (int nf = 0; nf < 3; ++nf) acc[mf][nf] = MFMA16(afr, bfrg[nf], acc[mf][nf]);
        }
      }
    }
    __builtin_amdgcn_s_setprio(0);
    if (kc < 10) {
      WAIT_OWN();
      SBAR();
    } else if (kc == 10) {
      asm volatile("s_waitcnt vmcnt(0)" ::: "memory");
      SBAR();
    }
  }

#pragma unroll
  for (int mf = 0; mf < 4; ++mf) {
    if (mf < mfn) {
#pragma unroll
      for (int nf = 0; nf < 3; ++nf) {
        int N = nt * 192 + wn * 48 + nf * 16 + r;
        float bb = bias[N];
#pragma unroll
        for (int rr = 0; rr < 4; ++rr) {
          int mrow = wm * 48 + mf * 16 + gq * 4 + rr;
          if (mrow < 197)  // never write into the next b's rows
            Out[((size_t)(b * 197 + mrow)) * 768 + N] = acc[mf][nf][rr] + bb;
        }
      }
    }
  }
#undef WAIT_OWN
}

extern "C" void kernel_launch(void* const* d_in, const int* in_sizes, int n_in,
                              void* d_out, int out_size, void* d_ws, size_t ws_size,
                              hipStream_t stream) {
  const float* x       = (const float*)d_in[0];
  const float* w_qkv   = (const float*)d_in[1];
  const float* b_qkv   = (const float*)d_in[2];
  const float* w_proj  = (const float*)d_in[3];
  const float* b_proj  = (const float*)d_in[4];
  const float* conv_qw = (const float*)d_in[5];
  const float* conv_qb = (const float*)d_in[6];
  const float* conv_kw = (const float*)d_in[7];
  const float* conv_kb = (const float*)d_in[8];
  float* out = (float*)d_out;

  char* ws = (char*)d_ws;
  size_t off = 0;
  auto alloc = [&](size_t n) {
    char* p = ws + off;
    off = (off + n + 255) & ~(size_t)255;
    return p;
  };
  // order matters: OOB tile reads from x_bf / ao_bf tails must land inside the workspace
  unsigned short* x_bf    = (unsigned short*)alloc(12608ull * 768 * 2);
  unsigned short* ao_bf   = (unsigned short*)alloc(12608ull * 768 * 2);
  unsigned short* wqkv_bf = (unsigned short*)alloc(2304ull * 768 * 2);
  unsigned short* wproj_bf= (unsigned short*)alloc(768ull * 768 * 2);
  float* tcpq = (float*)alloc(4ull * 64 * 768 * 4);
  float* tcpk = (float*)alloc(4ull * 64 * 768 * 4);
  if (off > ws_size) return;  // workspace too small; fail visibly

  // conv bias is applied inside qkv_attn's tcb loader via b_qkv? No: conv biases
  // (conv_qb/conv_kb) must be added to the partial sums. Fold them into the tcb
  // loader by passing them through: simplest is to add them here via partials —
  // instead we pre-add conv_qb/conv_kb into part 0 using a tiny trick: conv blocks
  // don't know bias; so qkv_attn adds bias[sec] + conv bias. To keep qkv signature
  // small we pre-combine: tcb needs b_qkv + conv_b + sum(partials). We pass
  // combined bias pointers below.
  // (b_qkv sections 0/1 and conv_qb/conv_kb are both per-channel constants; the
  //  qkv_attn tcb loader reads bias[sec*768+c]; we give it a combined buffer.)
  float* bias_comb = (float*)alloc(2304ull * 4);
  {
    // build combined bias on device with a tiny kernel-free approach: use cvt_conv's
    // cvt path? Keep it simple: small dedicated kernel below.
  }

  const int na4 = 2420736, nb4 = 442368, nc4 = 147456;
  const int cvt_blocks = (na4 + nb4 + nc4 + 255) / 256;
  cvt_conv<<<dim3(768 + cvt_blocks), 256, 0, stream>>>(
      x, x_bf, na4, w_qkv, wqkv_bf, nb4, w_proj, wproj_bf, nc4,
      conv_qw, conv_kw, tcpq, tcpk);
  // combine biases: bias_comb[c] = b_qkv[c] + (c<768 ? conv_qb[c] : c<1536 ? conv_kb[c-768] : 0)
  {
    struct L {
      static __global__ void k(const float* bq, const float* cq, const float* ck,
                               float* o) {
        int i = blockIdx.x * 256 + threadIdx.x;
        if (i >= 2304) return;
        float v = bq[i];
        if (i < 768) v += cq[i];
        else if (i < 1536) v += ck[i - 768];
        o[i] = v;
      }
    };
    L::k<<<dim3(9), 256, 0, stream>>>(b_qkv, conv_qb, conv_kb, bias_comb);
  }
  qkv_attn<<<dim3(768), 1024, 0, stream>>>(x_bf, wqkv_bf, bias_comb, tcpq, tcpk, ao_bf);
  proj_gemm<<<dim3(256), 1024, 0, stream>>>(ao_bf, wproj_bf, b_proj, out);
}